// Round 1
// baseline (168.190 us; speedup 1.0000x reference)
//
#include <hip/hip_runtime.h>

// Hausdorff adv2ori via MFMA: B=8, K=8192.
// dist(n,m) = oo_n + aa_m - 2*o.a  ->  C = mfma(A',B') = oo_n - 2*o.a  (fp16 hi/lo split)
// loss = mean_b( w_b * max_m min_n dist )
//
// K=16 slot packing (one 32x32x16_f16 MFMA per 32x32 pair tile):
//   A'(ori n): [oh.x oh.y oh.z | oh.x oh.y oh.z | ol.x ol.y ol.z | oo_h oo_l | 0 x5]
//   B'(adv m): [bh.x bh.y bh.z | bl.x bl.y bl.z | bh.x bh.y bh.z | 1    1    | 0 x5]
//   with b = -2*a, x = x_hi + x_lo fp16 splits. Dropped ol.bl terms ~1e-6;
//   oo split to fp16 hi/lo ~2e-6; total per-distance error ~1e-5 (fp32 accum).
//
// Workspace layout (needs ~4.3 MiB):
//   A' f16[8][8192][16]  @ 0        (2 MiB)
//   B' f16[8][8192][16]  @ 2 MiB    (2 MiB)
//   aa f32[8][8192]      @ 4 MiB    (256 KiB)
//   bred u32[16]         @ 4 MiB + 256 KiB   ([0..7]=batch max bits, [8]=counter)

#define KPTS 8192
#define BATCH 8
#define NTILES (KPTS / 32)                  // 256 n-tiles of 32 rows
#define MBLK 256                            // adv columns per block (4 waves x 64)
#define GRID_MAIN (BATCH * (KPTS / MBLK))   // 256 blocks -> 1 per CU

typedef _Float16 half8 __attribute__((ext_vector_type(8)));
typedef float f32x16 __attribute__((ext_vector_type(16)));

__global__ __launch_bounds__(256) void prep(const float* __restrict__ adv,
                                            const float* __restrict__ ori,
                                            _Float16* __restrict__ Ap,
                                            _Float16* __restrict__ Bp,
                                            float* __restrict__ aa,
                                            unsigned int* __restrict__ bred) {
    const int g = blockIdx.x * 256 + threadIdx.x;   // point id, 0..B*K-1
    if (blockIdx.x == 0 && threadIdx.x < 16) bred[threadIdx.x] = 0u;

    const _Float16 Z = (_Float16)0.0f;

    // --- ori side: A' ---
    float x = ori[3 * g + 0], y = ori[3 * g + 1], z = ori[3 * g + 2];
    float oo = x * x + y * y + z * z;
    _Float16 hx = (_Float16)x, hy = (_Float16)y, hz = (_Float16)z;
    _Float16 lx = (_Float16)(x - (float)hx);
    _Float16 ly = (_Float16)(y - (float)hy);
    _Float16 lz = (_Float16)(z - (float)hz);
    _Float16 oh = (_Float16)oo;
    _Float16 ol = (_Float16)(oo - (float)oh);
    half8 a0 = {hx, hy, hz, hx, hy, hz, lx, ly};
    half8 a1 = {lz, oh, ol, Z, Z, Z, Z, Z};
    *(half8*)(Ap + (size_t)g * 16)     = a0;
    *(half8*)(Ap + (size_t)g * 16 + 8) = a1;

    // --- adv side: B' (fold -2), aa in fp32 ---
    float ax = adv[3 * g + 0], ay = adv[3 * g + 1], az = adv[3 * g + 2];
    aa[g] = ax * ax + ay * ay + az * az;
    float tx = -2.0f * ax, ty = -2.0f * ay, tz = -2.0f * az;
    _Float16 bx = (_Float16)tx, by = (_Float16)ty, bz = (_Float16)tz;
    _Float16 cx = (_Float16)(tx - (float)bx);
    _Float16 cy = (_Float16)(ty - (float)by);
    _Float16 cz = (_Float16)(tz - (float)bz);
    const _Float16 ONE = (_Float16)1.0f;
    half8 b0 = {bx, by, bz, cx, cy, cz, bx, by};
    half8 b1 = {bz, ONE, ONE, Z, Z, Z, Z, Z};
    *(half8*)(Bp + (size_t)g * 16)     = b0;
    *(half8*)(Bp + (size_t)g * 16 + 8) = b1;
}

// min of 16 fp32, min3-friendly tree (8 v_min3 + 1 v_min expected).
__device__ __forceinline__ float min16(const f32x16 c) {
    float u0 = fminf(fminf(c[0],  c[1]),  c[2]);
    float u1 = fminf(fminf(c[3],  c[4]),  c[5]);
    float u2 = fminf(fminf(c[6],  c[7]),  c[8]);
    float u3 = fminf(fminf(c[9],  c[10]), c[11]);
    float u4 = fminf(fminf(c[12], c[13]), c[14]);
    float u5 = fminf(fminf(u0, u1), c[15]);
    float u6 = fminf(fminf(u2, u3), u4);
    return fminf(u5, u6);
}

// One block = one batch x 256 adv columns, loops all 8192 ori rows.
// Wave owns 64 columns (2 B-frags in regs) -> 2 MFMAs per 16B A-frag load.
// A-frags read direct from global (L2-resident: per-XCD working set ~2.3 MiB).
__global__ __launch_bounds__(256) void hausdorff(const _Float16* __restrict__ Ap,
                                                 const _Float16* __restrict__ Bp,
                                                 const float* __restrict__ aa,
                                                 const float* __restrict__ w,
                                                 unsigned int* __restrict__ bred,
                                                 float* __restrict__ out) {
    const int bid  = blockIdx.x;
    const int b    = bid >> 5;     // batch
    const int mb   = bid & 31;     // 256-column chunk
    const int tid  = threadIdx.x;
    const int lane = tid & 63;
    const int wv   = tid >> 6;
    const int r    = lane & 31;    // MFMA row/col within tile
    const int hk   = lane >> 5;    // K-half

    const size_t bK16 = (size_t)b * KPTS * 16;

    // B-fragments: col = lane&31, k = 8*(lane>>5)+[0..7] -> 16B contiguous.
    const int m0 = mb * MBLK + wv * 64 + r;
    const int m1 = m0 + 32;
    const half8 bf0 = *(const half8*)(Bp + bK16 + (size_t)m0 * 16 + hk * 8);
    const half8 bf1 = *(const half8*)(Bp + bK16 + (size_t)m1 * 16 + hk * 8);

    // A-fragment pointer: row = lane&31 within each 32-row tile.
    const _Float16* __restrict__ ap = Ap + bK16 + (size_t)r * 16 + (size_t)hk * 8;

    f32x16 zc;
#pragma unroll
    for (int i = 0; i < 16; ++i) zc[i] = 0.0f;

    float rm0 = __builtin_huge_valf();
    float rm1 = __builtin_huge_valf();

#pragma unroll 4
    for (int nt = 0; nt < NTILES; ++nt) {
        half8 af = *(const half8*)(ap + (size_t)nt * (32 * 16));  // +1 KiB/tile, coalesced
        f32x16 c0 = __builtin_amdgcn_mfma_f32_32x32x16_f16(af, bf0, zc, 0, 0, 0);
        f32x16 c1 = __builtin_amdgcn_mfma_f32_32x32x16_f16(af, bf1, zc, 0, 0, 0);
        rm0 = fminf(rm0, min16(c0));   // lane covers 16 of 32 rows; other half in lane^32
        rm1 = fminf(rm1, min16(c1));
    }

    // Complete min over all 32 rows of each tile (lane pair l, l^32 share a column).
    rm0 = fminf(rm0, __shfl_xor(rm0, 32, 64));
    rm1 = fminf(rm1, __shfl_xor(rm1, 32, 64));

    // + aa_m (fp32), clamp at 0 so uint ordering is valid (max is positive anyway).
    const float* aab = aa + (size_t)b * KPTS;
    float v = fmaxf(fmaxf(rm0 + aab[m0], 0.0f), fmaxf(rm1 + aab[m1], 0.0f));

    // max over the wave's 64 columns (halves are duplicates after the xor-min).
#pragma unroll
    for (int off = 16; off; off >>= 1)
        v = fmaxf(v, __shfl_xor(v, off, 64));
    if (lane == 0) atomicMax(&bred[b], __float_as_uint(v));  // nonneg float bits order as uint

    // Last block finalizes the weighted batch mean (no extra kernel).
    __syncthreads();
    if (tid == 0) {
        __threadfence();
        unsigned int done = atomicAdd(&bred[8], 1u);
        if (done == (unsigned int)(gridDim.x - 1)) {
            __threadfence();
            float s = 0.0f;
#pragma unroll
            for (int i = 0; i < BATCH; ++i)
                s += __uint_as_float(atomicMax(&bred[i], 0u)) * w[i];  // atomic read
            out[0] = s * (1.0f / BATCH);
        }
    }
}

extern "C" void kernel_launch(void* const* d_in, const int* in_sizes, int n_in,
                              void* d_out, int out_size, void* d_ws, size_t ws_size,
                              hipStream_t stream) {
    const float* adv = (const float*)d_in[0];   // [B, K, 3]
    const float* ori = (const float*)d_in[1];   // [B, K, 3]
    const float* w   = (const float*)d_in[2];   // [B]
    float* out = (float*)d_out;

    char* ws = (char*)d_ws;                     // needs ~4.3 MiB
    _Float16* Ap = (_Float16*)(ws);                                   // 2 MiB
    _Float16* Bp = (_Float16*)(ws + (size_t)(2 << 20));               // 2 MiB
    float*    aa = (float*)(ws + (size_t)(4 << 20));                  // 256 KiB
    unsigned int* bred = (unsigned int*)(ws + (size_t)(4 << 20) + (256 << 10));

    prep<<<(BATCH * KPTS) / 256, 256, 0, stream>>>(adv, ori, Ap, Bp, aa, bred);
    hausdorff<<<GRID_MAIN, 256, 0, stream>>>(Ap, Bp, aa, w, bred, out);
}

// Round 2
// 86.267 us; speedup vs baseline: 1.9496x; 1.9496x over previous
//
#include <hip/hip_runtime.h>

// Hausdorff adv2ori via MFMA: B=8, K=8192.
// dist(n,m) = oo_n + aa_m - 2*o.a ; C = mfma(A',B') = oo_n - 2*o.a (fp16 hi/lo split)
// loss = mean_b( w_b * max_m min_n dist )
//
// K=16 slot packing (one 32x32x16_f16 MFMA per 32x32 pair tile):
//   A'(ori n): [oh.x oh.y oh.z | oh.x oh.y oh.z | ol.x ol.y ol.z | oo_h oo_l | 0 x5]
//   B'(adv m): [bh.x bh.y bh.z | bl.x bl.y bl.z | bh.x bh.y bh.z | 1    1    | 0 x5]
//   b = -2*a; dropped ol.bl terms ~1e-6; fp32 accumulate. Verified absmax=0 in R1.
//
// R1 post-mortem: structure right, occupancy wrong (1 wave/SIMD -> latency-bound,
// MfmaUtil 5.8%). Fix: NSPLIT=8 row-split -> 2048 blocks (32 waves/CU), A' staged
// in LDS (global latency off the critical path), cross-slice min via filtered
// atomicMin on ws. A'/B' built in-kernel: prep dispatch deleted.

#define KPTS 8192
#define BATCH 8

#define CBLK 256              // adv columns per block (4 waves x 64)
#define NSPLIT 8              // row splits (cross-combined via ws atomicMin)
#define RBLK (KPTS / NSPLIT)  // 1024 ori rows per block
#define CHUNK 512             // rows staged in LDS at a time (16 KB)
#define NCHUNK (RBLK / CHUNK) // 2
#define CTILES (CHUNK / 32)   // 16 MFMA row-tiles per chunk

typedef _Float16 half8 __attribute__((ext_vector_type(8)));
typedef float f32x16 __attribute__((ext_vector_type(16)));

// min of 16 fp32 (compiler fuses to v_min3 tree) 
__device__ __forceinline__ float min16(const f32x16 c) {
    float u0 = fminf(fminf(c[0],  c[1]),  c[2]);
    float u1 = fminf(fminf(c[3],  c[4]),  c[5]);
    float u2 = fminf(fminf(c[6],  c[7]),  c[8]);
    float u3 = fminf(fminf(c[9],  c[10]), c[11]);
    float u4 = fminf(fminf(c[12], c[13]), c[14]);
    float u5 = fminf(fminf(u0, u1), c[15]);
    float u6 = fminf(fminf(u2, u3), u4);
    return fminf(u5, u6);
}

__global__ __launch_bounds__(256) void hausdorff(const float* __restrict__ adv,
                                                 const float* __restrict__ ori,
                                                 unsigned int* __restrict__ ws,
                                                 float* __restrict__ out) {
    __shared__ _Float16 sA[CHUNK * 16];   // A' slice: 32 B/row, 16 KB

    const int bid  = blockIdx.x;          // grid = 8 * 32 * 8 = 2048
    const int b    = bid >> 8;
    const int mc   = (bid >> 3) & 31;     // column chunk (256 cols)
    const int ns   = bid & 7;             // row split
    const int tid  = threadIdx.x;
    const int lane = tid & 63;
    const int wv   = tid >> 6;
    const int r    = lane & 31;           // MFMA row/col index
    const int hk   = lane >> 5;           // K-half

    if (bid == 0 && tid == 0) out[0] = 0.0f;   // for reduce's atomicAdd

    const _Float16 Z = (_Float16)0.0f, ONE = (_Float16)1.0f;

    // ---- B-fragments + aa from adv (once per block, registers) ----
    const float* advb = adv + (size_t)b * KPTS * 3;
    const int m0 = mc * CBLK + wv * 64 + r;
    const int m1 = m0 + 32;
    half8 bf0, bf1;
    float aa0, aa1;
    {
        float ax = advb[3 * m0], ay = advb[3 * m0 + 1], az = advb[3 * m0 + 2];
        aa0 = ax * ax + ay * ay + az * az;
        float tx = -2.f * ax, ty = -2.f * ay, tz = -2.f * az;
        _Float16 bx = (_Float16)tx, by = (_Float16)ty, bz = (_Float16)tz;
        _Float16 cx = (_Float16)(tx - (float)bx);
        _Float16 cy = (_Float16)(ty - (float)by);
        _Float16 cz = (_Float16)(tz - (float)bz);
        half8 h0 = {bx, by, bz, cx, cy, cz, bx, by};
        half8 h1 = {bz, ONE, ONE, Z, Z, Z, Z, Z};
        bf0 = hk ? h1 : h0;
    }
    {
        float ax = advb[3 * m1], ay = advb[3 * m1 + 1], az = advb[3 * m1 + 2];
        aa1 = ax * ax + ay * ay + az * az;
        float tx = -2.f * ax, ty = -2.f * ay, tz = -2.f * az;
        _Float16 bx = (_Float16)tx, by = (_Float16)ty, bz = (_Float16)tz;
        _Float16 cx = (_Float16)(tx - (float)bx);
        _Float16 cy = (_Float16)(ty - (float)by);
        _Float16 cz = (_Float16)(tz - (float)bz);
        half8 h0 = {bx, by, bz, cx, cy, cz, bx, by};
        half8 h1 = {bz, ONE, ONE, Z, Z, Z, Z, Z};
        bf1 = hk ? h1 : h0;
    }

    f32x16 zc;
#pragma unroll
    for (int i = 0; i < 16; ++i) zc[i] = 0.0f;

    float rm0 = __builtin_huge_valf();
    float rm1 = __builtin_huge_valf();

    const float* orib = ori + (size_t)b * KPTS * 3;
    const _Float16* apl = sA + r * 16 + hk * 8;   // per-lane A-frag base in LDS

    for (int ch = 0; ch < NCHUNK; ++ch) {
        const int rowbase = ns * RBLK + ch * CHUNK;

        __syncthreads();   // protect sA reuse across chunks
        // ---- stage + convert 512 ori rows into LDS A' layout ----
        for (int rr = tid; rr < CHUNK; rr += 256) {
            const float* op = orib + (size_t)(rowbase + rr) * 3;
            float x = op[0], y = op[1], z = op[2];
            float oo = x * x + y * y + z * z;
            _Float16 hx = (_Float16)x, hy = (_Float16)y, hz = (_Float16)z;
            _Float16 lx = (_Float16)(x - (float)hx);
            _Float16 ly = (_Float16)(y - (float)hy);
            _Float16 lz = (_Float16)(z - (float)hz);
            _Float16 oh = (_Float16)oo;
            _Float16 ol = (_Float16)(oo - (float)oh);
            half8 a0 = {hx, hy, hz, hx, hy, hz, lx, ly};
            half8 a1 = {lz, oh, ol, Z, Z, Z, Z, Z};
            *(half8*)(sA + rr * 16)     = a0;
            *(half8*)(sA + rr * 16 + 8) = a1;
        }
        __syncthreads();

        // ---- 16 row-tiles: ds_read_b128 + 2 MFMA + min-tree each ----
#pragma unroll 4
        for (int t = 0; t < CTILES; ++t) {
            half8 af = *(const half8*)(apl + (size_t)t * (32 * 16));
            f32x16 c0 = __builtin_amdgcn_mfma_f32_32x32x16_f16(af, bf0, zc, 0, 0, 0);
            f32x16 c1 = __builtin_amdgcn_mfma_f32_32x32x16_f16(af, bf1, zc, 0, 0, 0);
            rm0 = fminf(rm0, min16(c0));
            rm1 = fminf(rm1, min16(c1));
        }
    }

    // complete the 32-row min (lane pair l, l^32 share a column)
    rm0 = fminf(rm0, __shfl_xor(rm0, 32, 64));
    rm1 = fminf(rm1, __shfl_xor(rm1, 32, 64));

    float v0 = fmaxf(rm0 + aa0, 0.0f);   // clamp: keep nonneg for uint ordering
    float v1 = fmaxf(rm1 + aa1, 0.0f);

    // cross-slice min combine; filter first to cut atomic traffic ~2-4x
    unsigned int* wsb = ws + (size_t)b * KPTS;
    if (hk == 0) {
        unsigned int u0 = __float_as_uint(v0);
        if (u0 < wsb[m0]) atomicMin(wsb + m0, u0);
        unsigned int u1 = __float_as_uint(v1);
        if (u1 < wsb[m1]) atomicMin(wsb + m1, u1);
    }
}

// One block per batch: max over m, weighted mean into out.
__global__ __launch_bounds__(1024) void reduceB(const unsigned int* __restrict__ ws,
                                                const float* __restrict__ w,
                                                float* __restrict__ out) {
    const int b = blockIdx.x;
    const int tid = threadIdx.x;

    float mx = 0.0f;
#pragma unroll
    for (int m = tid; m < KPTS; m += 1024)
        mx = fmaxf(mx, __uint_as_float(ws[(size_t)b * KPTS + m]));

#pragma unroll
    for (int off = 32; off; off >>= 1)
        mx = fmaxf(mx, __shfl_down(mx, off, 64));

    __shared__ float red[16];
    if ((tid & 63) == 0) red[tid >> 6] = mx;
    __syncthreads();
    if (tid == 0) {
        float m2 = red[0];
#pragma unroll
        for (int i = 1; i < 16; ++i) m2 = fmaxf(m2, red[i]);
        atomicAdd(out, m2 * w[b] * (1.0f / BATCH));
    }
}

extern "C" void kernel_launch(void* const* d_in, const int* in_sizes, int n_in,
                              void* d_out, int out_size, void* d_ws, size_t ws_size,
                              hipStream_t stream) {
    const float* adv = (const float*)d_in[0];   // [B, K, 3]
    const float* ori = (const float*)d_in[1];   // [B, K, 3]
    const float* w   = (const float*)d_in[2];   // [B]
    float* out = (float*)d_out;
    unsigned int* ws = (unsigned int*)d_ws;     // B*K uints = 256 KB

    // 0xFFFFFFFF = top element for uint-ordered nonneg-float min
    hipMemsetAsync(ws, 0xFF, (size_t)BATCH * KPTS * sizeof(unsigned int), stream);
    hausdorff<<<BATCH * 32 * NSPLIT, 256, 0, stream>>>(adv, ori, ws, out);
    reduceB<<<BATCH, 1024, 0, stream>>>((const unsigned int*)ws, w, out);
}